// Round 1
// 294.816 us; speedup vs baseline: 1.0273x; 1.0273x over previous
//
#include <hip/hip_runtime.h>
#include <cstddef>

#define WLEN 16384
#define SCALEQ 0.17677669529663687f       // 32^-0.5
#define CB_SCALE 16777216.0f              // 2^24 (keeps C_b out of fp16 subnormals)
#define CB_INV   5.9604644775390625e-08f  // 2^-24

typedef _Float16 half8 __attribute__((ext_vector_type(8)));
typedef _Float16 half4 __attribute__((ext_vector_type(4)));
typedef _Float16 half2v __attribute__((ext_vector_type(2)));
typedef float float4v __attribute__((ext_vector_type(4)));

// ws float offsets
#define WS_CTX 0         // 16*4*32*32 = 65536 floats (zeroed)
#define WS_DEN 65536     // 16*4*32    = 2048  floats (zeroed)
#define WS_CB  67584     // C_b fp16 [16][128][128] = 262144 halfs = 131072 floats

#define MFMA16(a, b, c) __builtin_amdgcn_mfma_f32_16x16x32_f16(a, b, c, 0, 0, 0)

__device__ __forceinline__ half8 cvt8(float4 w0, float4 w1) {
  half8 h;
  h[0] = (_Float16)w0.x; h[1] = (_Float16)w0.y;
  h[2] = (_Float16)w0.z; h[3] = (_Float16)w0.w;
  h[4] = (_Float16)w1.x; h[5] = (_Float16)w1.y;
  h[6] = (_Float16)w1.z; h[7] = (_Float16)w1.w;
  return h;
}

// KA: k/v projection (f16 MFMA) + exp(k) + ctx = ek @ v^T (f16 MFMA) + den
// grid (32 chunks, 16 b), block 256 = 4 waves, wave w <-> head w
// chunk = 512 positions, subtile = 32 positions
// Double-buffered x staging: loads for tile t+1 issued before compute of t
// (T14 async-split), LDS writes after compute. ONE barrier per subtile.
__global__ __launch_bounds__(256, 2) void ka_ctx(
    const float* __restrict__ x, const float* __restrict__ Wqkv,
    float* __restrict__ ws) {
  __shared__ __align__(16) _Float16 xh[2][32 * 136];  // x^T tiles [n][c], pad 136
  __shared__ __align__(16) _Float16 ekl[4 * 32 * 40]; // per-wave [d][n], pad 40
  __shared__ __align__(16) _Float16 vl[4 * 32 * 40];  // per-wave [e][n], pad 40
  const int tid = threadIdx.x;
  const int lane = tid & 63, wv = tid >> 6;
  const int l15 = lane & 15, quad = lane >> 4;
  const int b = blockIdx.y, chunk = blockIdx.x;
  float* ctx = ws + WS_CTX;
  float* den = ws + WS_DEN;
  const float* xb = x + (size_t)b * 128 * WLEN;

  // weights stationary, converted fp32->fp16 in-regs (Wqkv is L2-resident):
  // 4 mtiles (mt 0,1 = k rows; 2,3 = v rows) x 4 ksteps
  half8 afr[4][4];
  #pragma unroll
  for (int mt = 0; mt < 4; ++mt) {
    int row = (mt < 2) ? (128 + 32 * wv + mt * 16 + l15)
                       : (256 + 32 * wv + (mt - 2) * 16 + l15);
    #pragma unroll
    for (int ks = 0; ks < 4; ++ks) {
      const float* wp = Wqkv + row * 128 + ks * 32 + quad * 8;
      afr[mt][ks] = cvt8(*(const float4*)wp, *(const float4*)(wp + 4));
    }
  }

  // staging decomposition: idx = it*256+tid -> f = n-group(4), cp = c-pair
  const int f0 = tid & 7;
  const int cp0 = tid >> 3;        // it=0: 0..31
  const int cp1 = cp0 + 32;        // it=1: 32..63
  float4 pa0, pc0, pa1, pc1;       // prefetch regs (held across compute)

  auto LOADT = [&](int s) {
    const float* base = xb + chunk * 512 + s * 32 + 4 * f0;
    pa0 = *(const float4*)(base + (size_t)(2 * cp0) * WLEN);
    pc0 = *(const float4*)(base + (size_t)(2 * cp0 + 1) * WLEN);
    pa1 = *(const float4*)(base + (size_t)(2 * cp1) * WLEN);
    pc1 = *(const float4*)(base + (size_t)(2 * cp1 + 1) * WLEN);
  };
  auto CVTW = [&](int bsel) {
    _Float16* xd = xh[bsel];
    float av0[4] = {pa0.x, pa0.y, pa0.z, pa0.w};
    float cv0[4] = {pc0.x, pc0.y, pc0.z, pc0.w};
    float av1[4] = {pa1.x, pa1.y, pa1.z, pa1.w};
    float cv1[4] = {pc1.x, pc1.y, pc1.z, pc1.w};
    #pragma unroll
    for (int i = 0; i < 4; ++i) {
      half2v h0; h0[0] = (_Float16)av0[i]; h0[1] = (_Float16)cv0[i];
      *(half2v*)&xd[(4 * f0 + i) * 136 + 2 * cp0] = h0;
      half2v h1; h1[0] = (_Float16)av1[i]; h1[1] = (_Float16)cv1[i];
      *(half2v*)&xd[(4 * f0 + i) * 136 + 2 * cp1] = h1;
    }
  };

  const float4v zero4 = {0.f, 0.f, 0.f, 0.f};
  float4v ctxa[2][2] = {zero4, zero4, zero4, zero4};
  float denr[8] = {0.f, 0.f, 0.f, 0.f, 0.f, 0.f, 0.f, 0.f};

  LOADT(0);
  CVTW(0);
  for (int s = 0; s < 16; ++s) {
    __syncthreads();                 // xh[s&1] fully staged; prev compute done
    if (s < 15) LOADT(s + 1);        // issue next-tile global loads early
    const _Float16* xc = xh[s & 1];
    // k/v projection: M=64 (wave rows), N=32, K=128
    float4v acc[4][2] = {zero4, zero4, zero4, zero4, zero4, zero4, zero4, zero4};
    #pragma unroll
    for (int ks = 0; ks < 4; ++ks) {
      half8 b0 = *(const half8*)&xc[l15 * 136 + ks * 32 + quad * 8];
      half8 b1 = *(const half8*)&xc[(16 + l15) * 136 + ks * 32 + quad * 8];
      #pragma unroll
      for (int mt = 0; mt < 4; ++mt) {
        acc[mt][0] = MFMA16(afr[mt][ks], b0, acc[mt][0]);
        acc[mt][1] = MFMA16(afr[mt][ks], b1, acc[mt][1]);
      }
    }
    // ek (with den partials) and v -> per-wave LDS [row][n]
    #pragma unroll
    for (int mt = 0; mt < 2; ++mt)
      #pragma unroll
      for (int nt = 0; nt < 2; ++nt)
        #pragma unroll
        for (int r = 0; r < 4; ++r) {
          float e = __expf(acc[mt][nt][r]);
          denr[mt * 4 + r] += e;
          ekl[(wv * 32 + mt * 16 + quad * 4 + r) * 40 + nt * 16 + l15] = (_Float16)e;
        }
    #pragma unroll
    for (int mt = 0; mt < 2; ++mt)
      #pragma unroll
      for (int nt = 0; nt < 2; ++nt)
        #pragma unroll
        for (int r = 0; r < 4; ++r)
          vl[(wv * 32 + mt * 16 + quad * 4 + r) * 40 + nt * 16 + l15] =
              (_Float16)acc[mt + 2][nt][r];
    // ctx += ek @ v^T : M=32 d, N=32 e, K=32 n (wave-private, no barrier)
    half8 ae0 = *(const half8*)&ekl[(wv * 32 + l15) * 40 + quad * 8];
    half8 ae1 = *(const half8*)&ekl[(wv * 32 + 16 + l15) * 40 + quad * 8];
    half8 bv0 = *(const half8*)&vl[(wv * 32 + l15) * 40 + quad * 8];
    half8 bv1 = *(const half8*)&vl[(wv * 32 + 16 + l15) * 40 + quad * 8];
    ctxa[0][0] = MFMA16(ae0, bv0, ctxa[0][0]);
    ctxa[0][1] = MFMA16(ae0, bv1, ctxa[0][1]);
    ctxa[1][0] = MFMA16(ae1, bv0, ctxa[1][0]);
    ctxa[1][1] = MFMA16(ae1, bv1, ctxa[1][1]);
    if (s < 15) CVTW((s + 1) & 1);   // stage next tile into the other buffer
  }
  // reduce to global
  #pragma unroll
  for (int dt = 0; dt < 2; ++dt)
    #pragma unroll
    for (int et = 0; et < 2; ++et)
      #pragma unroll
      for (int r = 0; r < 4; ++r)
        atomicAdd(&ctx[((b * 4 + wv) * 32 + dt * 16 + quad * 4 + r) * 32 +
                       et * 16 + l15],
                  ctxa[dt][et][r]);
  #pragma unroll
  for (int i = 0; i < 8; ++i) {
    float v = denr[i];
    v += __shfl_xor(v, 1, 64);
    v += __shfl_xor(v, 2, 64);
    v += __shfl_xor(v, 4, 64);
    v += __shfl_xor(v, 8, 64);
    if (l15 == 0)
      atomicAdd(&den[(b * 4 + wv) * 32 + (i >> 2) * 16 + quad * 4 + (i & 3)], v);
  }
}

// KB: C_b[o][hd] = sum_e Wout[o][h*32+e] * ctx[b,h][d][e]/(den*W), *2^24 -> fp16
// grid (16 b, 4 h): 4x the parallelism of the old single-b version
__global__ __launch_bounds__(256) void kb_cb(
    const float* __restrict__ Wout, float* __restrict__ ws) {
  __shared__ float nc[1024];
  const int b = blockIdx.x, h = blockIdx.y, tid = threadIdx.x;
  const float* ctx = ws + WS_CTX;
  const float* den = ws + WS_DEN;
  _Float16* cb = (_Float16*)(ws + WS_CB) + b * 16384;
  for (int i = tid; i < 1024; i += 256) {
    int d = i >> 5;
    nc[i] = ctx[((b * 4 + h) * 32 + d) * 32 + (i & 31)] /
            (den[(b * 4 + h) * 32 + d] * 16384.0f);
  }
  __syncthreads();
  const int o = tid >> 1, dh = (tid & 1) * 16;
  float wrow[32];
  #pragma unroll
  for (int e4 = 0; e4 < 8; ++e4) {
    float4 w4 = *(const float4*)(Wout + o * 128 + h * 32 + e4 * 4);
    wrow[e4 * 4 + 0] = w4.x; wrow[e4 * 4 + 1] = w4.y;
    wrow[e4 * 4 + 2] = w4.z; wrow[e4 * 4 + 3] = w4.w;
  }
  for (int d = 0; d < 16; ++d) {
    const float* ncr = &nc[(dh + d) * 32];
    float acc = 0.f;
    #pragma unroll
    for (int e = 0; e < 32; ++e) acc += wrow[e] * ncr[e];
    cb[o * 128 + h * 32 + dh + d] = (_Float16)(acc * CB_SCALE);
  }
}

// KC: q-proj MFMA -> per-head softmax (in regs) -> LDS roundtrip ->
//     C_b MFMA -> +b_out -> channel LayerNorm -> store
// grid (128 tiles, 16 b), block 256 = 4 waves, wave w <-> head w / o-strip w
__global__ __launch_bounds__(256, 2) void kc_out(
    const float* __restrict__ x, const float* __restrict__ Wqkv,
    const float* __restrict__ wsc, const float* __restrict__ b_out,
    const float* __restrict__ gamma, const float* __restrict__ beta,
    float* __restrict__ out) {
  __shared__ __align__(16) _Float16 xh[128 * 136];  // x^T tile, reused as q_l[n][hd]
  __shared__ float ssum[4][128], ssq[4][128];
  __shared__ float smean[128], sinv[128];
  const int tid = threadIdx.x;
  const int lane = tid & 63, wv = tid >> 6;
  const int l15 = lane & 15, quad = lane >> 4;
  const int b = blockIdx.y, tile = blockIdx.x;
  const int n0 = tile * 128;
  const _Float16* cb = (const _Float16*)(wsc + WS_CB) + b * 16384;
  const float* xb = x + (size_t)b * 128 * WLEN;
  const float4v zero4 = {0.f, 0.f, 0.f, 0.f};

  // phase-1 A-frags: q rows 32*wv .. +31 (head wv), fp32->fp16 in-regs
  half8 a1[2][4];
  #pragma unroll
  for (int mt = 0; mt < 2; ++mt)
    #pragma unroll
    for (int ks = 0; ks < 4; ++ks) {
      const float* wp = Wqkv + (32 * wv + mt * 16 + l15) * 128 + ks * 32 + quad * 8;
      a1[mt][ks] = cvt8(*(const float4*)wp, *(const float4*)(wp + 4));
    }

  // stage x fp32 [c][n] -> fp16 [n][c]
  #pragma unroll
  for (int it = 0; it < 8; ++it) {
    int idx = it * 256 + tid;
    int f = (idx & 7) | ((idx >> 9) << 3);  // n-group 0..31
    int cp = (idx >> 3) & 63;               // c-pair 0..63
    const float* p0 = xb + (size_t)(2 * cp) * WLEN + n0 + 4 * f;
    float4 a = *(const float4*)p0;
    float4 c = *(const float4*)(p0 + WLEN);
    float av[4] = {a.x, a.y, a.z, a.w};
    float cv[4] = {c.x, c.y, c.z, c.w};
    #pragma unroll
    for (int i = 0; i < 4; ++i) {
      half2v h; h[0] = (_Float16)av[i]; h[1] = (_Float16)cv[i];
      *(half2v*)&xh[(4 * f + i) * 136 + 2 * cp] = h;
    }
  }
  __syncthreads();

  // phase 1: q_raw = Wq @ x : per wave M=32, N=128, K=128
  float4v acc[2][8] = {zero4, zero4, zero4, zero4, zero4, zero4, zero4, zero4,
                       zero4, zero4, zero4, zero4, zero4, zero4, zero4, zero4};
  #pragma unroll
  for (int ks = 0; ks < 4; ++ks) {
    half8 bf[8];
    #pragma unroll
    for (int nt = 0; nt < 8; ++nt)
      bf[nt] = *(const half8*)&xh[(nt * 16 + l15) * 136 + ks * 32 + quad * 8];
    #pragma unroll
    for (int mt = 0; mt < 2; ++mt)
      #pragma unroll
      for (int nt = 0; nt < 8; ++nt)
        acc[mt][nt] = MFMA16(a1[mt][ks], bf[nt], acc[mt][nt]);
  }
  // softmax over d (32 rows of this wave) per column, then * SCALE
  #pragma unroll
  for (int nt = 0; nt < 8; ++nt) {
    float mx = -1e30f;
    #pragma unroll
    for (int mt = 0; mt < 2; ++mt)
      #pragma unroll
      for (int r = 0; r < 4; ++r) mx = fmaxf(mx, acc[mt][nt][r]);
    mx = fmaxf(mx, __shfl_xor(mx, 16, 64));
    mx = fmaxf(mx, __shfl_xor(mx, 32, 64));
    float sm = 0.f;
    #pragma unroll
    for (int mt = 0; mt < 2; ++mt)
      #pragma unroll
      for (int r = 0; r < 4; ++r) {
        float e = __expf(acc[mt][nt][r] - mx);
        acc[mt][nt][r] = e;
        sm += e;
      }
    sm += __shfl_xor(sm, 16, 64);
    sm += __shfl_xor(sm, 32, 64);
    float sc = SCALEQ / sm;
    #pragma unroll
    for (int mt = 0; mt < 2; ++mt)
      #pragma unroll
      for (int r = 0; r < 4; ++r) acc[mt][nt][r] *= sc;
  }
  __syncthreads();  // all waves done reading xh as x
  // write q_sm -> q_l[n][hd] (same buffer)
  #pragma unroll
  for (int mt = 0; mt < 2; ++mt)
    #pragma unroll
    for (int nt = 0; nt < 8; ++nt) {
      half4 hq;
      #pragma unroll
      for (int r = 0; r < 4; ++r) hq[r] = (_Float16)acc[mt][nt][r];
      *(half4*)&xh[(nt * 16 + l15) * 136 + 32 * wv + mt * 16 + quad * 4] = hq;
    }
  __syncthreads();

  // phase 2: y = C_b @ q_sm : per wave M=32 (o-strip), N=128, K=128
  half8 a2[2][4];
  #pragma unroll
  for (int mt = 0; mt < 2; ++mt)
    #pragma unroll
    for (int ks = 0; ks < 4; ++ks)
      a2[mt][ks] = *(const half8*)(cb + (32 * wv + mt * 16 + l15) * 128 +
                                   ks * 32 + quad * 8);
  float4v acc2[2][8] = {zero4, zero4, zero4, zero4, zero4, zero4, zero4, zero4,
                        zero4, zero4, zero4, zero4, zero4, zero4, zero4, zero4};
  #pragma unroll
  for (int ks = 0; ks < 4; ++ks) {
    half8 bf[8];
    #pragma unroll
    for (int nt = 0; nt < 8; ++nt)
      bf[nt] = *(const half8*)&xh[(nt * 16 + l15) * 136 + ks * 32 + quad * 8];
    #pragma unroll
    for (int mt = 0; mt < 2; ++mt)
      #pragma unroll
      for (int nt = 0; nt < 8; ++nt)
        acc2[mt][nt] = MFMA16(a2[mt][ks], bf[nt], acc2[mt][nt]);
  }

  // epilogue: unscale, +b_out, LN stats
  float bo[8], ga[8], be[8];
  #pragma unroll
  for (int mt = 0; mt < 2; ++mt)
    #pragma unroll
    for (int r = 0; r < 4; ++r) {
      int o = 32 * wv + mt * 16 + quad * 4 + r;
      bo[mt * 4 + r] = b_out[o];
      ga[mt * 4 + r] = gamma[o];
      be[mt * 4 + r] = beta[o];
    }
  #pragma unroll
  for (int nt = 0; nt < 8; ++nt) {
    float ps = 0.f, pq = 0.f;
    #pragma unroll
    for (int mt = 0; mt < 2; ++mt)
      #pragma unroll
      for (int r = 0; r < 4; ++r) {
        float v = acc2[mt][nt][r] * CB_INV + bo[mt * 4 + r];
        acc2[mt][nt][r] = v;
        ps += v;
        pq += v * v;
      }
    ps += __shfl_xor(ps, 16, 64);
    ps += __shfl_xor(ps, 32, 64);
    pq += __shfl_xor(pq, 16, 64);
    pq += __shfl_xor(pq, 32, 64);
    if (quad == 0) {
      ssum[wv][nt * 16 + l15] = ps;
      ssq[wv][nt * 16 + l15] = pq;
    }
  }
  __syncthreads();
  if (tid < 128) {
    float s = ssum[0][tid] + ssum[1][tid] + ssum[2][tid] + ssum[3][tid];
    float q2 = ssq[0][tid] + ssq[1][tid] + ssq[2][tid] + ssq[3][tid];
    float mean = s * (1.0f / 128.0f);
    float var = q2 * (1.0f / 128.0f) - mean * mean;
    smean[tid] = mean;
    sinv[tid] = rsqrtf(var + 1e-5f);
  }
  __syncthreads();
  float* ob = out + (size_t)b * 128 * WLEN + n0;
  #pragma unroll
  for (int nt = 0; nt < 8; ++nt) {
    int n = nt * 16 + l15;
    float mean = smean[n], inv = sinv[n];
    #pragma unroll
    for (int mt = 0; mt < 2; ++mt)
      #pragma unroll
      for (int r = 0; r < 4; ++r) {
        int o = 32 * wv + mt * 16 + quad * 4 + r;
        ob[(size_t)o * WLEN + n] =
            (acc2[mt][nt][r] - mean) * inv * ga[mt * 4 + r] + be[mt * 4 + r];
      }
  }
}

extern "C" void kernel_launch(void* const* d_in, const int* in_sizes, int n_in,
                              void* d_out, int out_size, void* d_ws, size_t ws_size,
                              hipStream_t stream) {
  const float* x    = (const float*)d_in[0];
  const float* Wqkv = (const float*)d_in[1];
  const float* Wout = (const float*)d_in[2];
  const float* bo   = (const float*)d_in[3];
  const float* gam  = (const float*)d_in[4];
  const float* bet  = (const float*)d_in[5];
  float* out = (float*)d_out;
  float* ws  = (float*)d_ws;

  hipMemsetAsync(ws, 0, (65536 + 2048) * sizeof(float), stream);
  hipLaunchKernelGGL(ka_ctx, dim3(32, 16), dim3(256), 0, stream, x, Wqkv, ws);
  hipLaunchKernelGGL(kb_cb, dim3(16, 4), dim3(256), 0, stream, Wout, ws);
  hipLaunchKernelGGL(kc_out, dim3(128, 16), dim3(256), 0, stream,
                     x, Wqkv, ws, bo, gam, bet, out);
}